// Round 2
// baseline (80904.376 us; speedup 1.0000x reference)
//
#include <hip/hip_runtime.h>
#include <stdint.h>

// CharLSTM persistent-RNN kernel for MI355X. f32 in / f32 out.
// 256 WGs (1/CU) x 512 threads. Wave v of WG w owns neuron j = 8w+v.
// R9:  conflict-free stride-64 fragment layout (bank-conflict-free LDS reads,
//      coalesced weight preload).
// R10: flag hierarchy — measured: only -6.5%. Congestion theory refuted
//      (mandatory traffic is ~0.9 TB/s, far below LLC capacity).
// R11: latency-chain attack. The flag layer ADDED one LLC hop to the serial
//      chain (h visible -> flag visible -> h fetched). Revert to single-hop
//      direct tagged polling: data arrives WITH validity. Also:
//        - x-part of the gate dot (32 FMAs) moved BEFORE the h wait: x only
//          depends on emb[seq[t]] (L2-resident), so it hides under the
//          in-flight h loads. x_lds deleted; ONE barrier per step.
//        - issue order: x global loads first, then h tagged loads, so the
//          x-dot's vmcnt wait leaves the h loads outstanding.
// h exchanged via tagged 64-bit agent-scope words: (f32<<32)|(step tag).

#define T_STEPS 16384
#define HID     2048
#define EMBD    512
#define NCH     128
#define FANIN   (EMBD + HID)
#define NBLK    256
#define TPB     512
#define NEUR_PER_WG 8

static_assert(TPB == EMBD, "index math assumes TPB == EMBD");

__device__ __forceinline__ float sigmoid_f(float x) {
  return 1.0f / (1.0f + __expf(-x));
}
__device__ __forceinline__ float tanh_f(float x) {
  return 1.0f - 2.0f / (__expf(2.0f * x) + 1.0f);
}
__device__ __forceinline__ unsigned long long ld_agent64(const unsigned long long* p) {
  return __hip_atomic_load(p, __ATOMIC_RELAXED, __HIP_MEMORY_SCOPE_AGENT);
}
__device__ __forceinline__ void st_agent64(unsigned long long* p, unsigned long long v) {
  __hip_atomic_store(p, v, __ATOMIC_RELAXED, __HIP_MEMORY_SCOPE_AGENT);
}

__global__ __launch_bounds__(TPB) void lstm_persist(
    const int* __restrict__ seq,
    const float* __restrict__ emb,
    const float* __restrict__ Wf, const float* __restrict__ bfv,
    const float* __restrict__ Wi, const float* __restrict__ biv,
    const float* __restrict__ Wg, const float* __restrict__ bgv,
    const float* __restrict__ Wo, const float* __restrict__ bov,
    const float* __restrict__ Wfc, const float* __restrict__ bfc,
    unsigned long long* __restrict__ hbuf,   // [2][HID] tagged h
    float* __restrict__ out)                 // f32: [T][NCH] logits, h[HID], c[HID]
{
  __shared__ float h_lds[2][HID];

  const int tid  = threadIdx.x;
  const int wv   = tid >> 6;
  const int lane = tid & 63;
  const int j    = blockIdx.x * NEUR_PER_WG + wv;   // neuron this wave owns

  // seq dtype guard (selects int32 on this data; kept for safety)
  int shift = 1;
  for (int k = 0; k < 64; ++k) {
    if (seq[2 * k + 1] != 0) { shift = 0; break; }
  }

  // ---- preload weights, stride-64 layout: lane l owns cols {k*64+l} ----
  // (coalesced global reads; conflict-free LDS reads in the gate loop)
  const float* Wmat[4] = {Wf, Wi, Wg, Wo};
  const float* bvec[4] = {bfv, biv, bgv, bov};
  float wh[4][32], wx[4][8], bias[4];
  #pragma unroll
  for (int g = 0; g < 4; ++g) {
    const float* rp = Wmat[g] + (size_t)j * FANIN;
    #pragma unroll
    for (int k = 0; k < 32; ++k) wh[g][k] = rp[EMBD + k * 64 + lane];
    #pragma unroll
    for (int k = 0; k < 8; ++k)  wx[g][k] = rp[k * 64 + lane];
    bias[g] = bvec[g][j];
  }

  // ---- logits duty: even WGs' wave 1 each own one output column ----
  // (wave1's extra work rides in its wait-slack, not on the critical path)
  int lcol = -1;
  float wfc_c[32];
  float bfc_c = 0.0f;
  if (((blockIdx.x & 1) == 0) && wv == 1) {
    lcol = blockIdx.x >> 1;                 // 0..127
    const float* wp = Wfc + (size_t)lcol * HID;
    #pragma unroll
    for (int u = 0; u < 32; ++u) wfc_c[u] = wp[u * 64 + lane];
    bfc_c = bfc[lcol];
  }

  float creg = 0.0f;  // cell state (lane 0 only)
  const int i0 = tid, i1 = tid + TPB, i2 = tid + 2 * TPB, i3 = tid + 3 * TPB;

  for (int t = 0; t < T_STEPS; ++t) {
    const int bsel = t & 1;
    const unsigned long long* src = hbuf + (size_t)bsel * HID;
    const unsigned ut = (unsigned)t;

    // ---- x loads first (L2-resident emb row, coalesced) ----
    const int s = seq[(size_t)t << shift];
    const float* xr = emb + (size_t)s * EMBD;
    float xv0 = xr[0 * 64 + lane], xv1 = xr[1 * 64 + lane],
          xv2 = xr[2 * 64 + lane], xv3 = xr[3 * 64 + lane],
          xv4 = xr[4 * 64 + lane], xv5 = xr[5 * 64 + lane],
          xv6 = xr[6 * 64 + lane], xv7 = xr[7 * 64 + lane];

    // ---- then issue the 4 tagged h loads (stay outstanding during x-dot) ----
    unsigned long long v0 = ld_agent64(src + i0), v1 = ld_agent64(src + i1),
                       v2 = ld_agent64(src + i2), v3 = ld_agent64(src + i3);

    // ---- x-part of the gate dots: independent of h, hides h latency ----
    float a0 = 0.0f, a1 = 0.0f, a2 = 0.0f, a3 = 0.0f;
    {
      const float xs[8] = {xv0, xv1, xv2, xv3, xv4, xv5, xv6, xv7};
      #pragma unroll
      for (int k = 0; k < 8; ++k) {
        a0 = fmaf(wx[0][k], xs[k], a0); a1 = fmaf(wx[1][k], xs[k], a1);
        a2 = fmaf(wx[2][k], xs[k], a2); a3 = fmaf(wx[3][k], xs[k], a3);
      }
    }

    // ---- single-hop readiness: poll own tagged words, re-issue missing ----
    while (((unsigned)v0 != ut) | ((unsigned)v1 != ut) |
           ((unsigned)v2 != ut) | ((unsigned)v3 != ut)) {
      if ((unsigned)v0 != ut) v0 = ld_agent64(src + i0);
      if ((unsigned)v1 != ut) v1 = ld_agent64(src + i1);
      if ((unsigned)v2 != ut) v2 = ld_agent64(src + i2);
      if ((unsigned)v3 != ut) v3 = ld_agent64(src + i3);
    }
    h_lds[bsel][i0] = __uint_as_float((unsigned)(v0 >> 32));
    h_lds[bsel][i1] = __uint_as_float((unsigned)(v1 >> 32));
    h_lds[bsel][i2] = __uint_as_float((unsigned)(v2 >> 32));
    h_lds[bsel][i3] = __uint_as_float((unsigned)(v3 >> 32));
    __syncthreads();

    // ---- h-part of the gate dots; stride-64 reads are conflict-free ----
    const float* hp = &h_lds[bsel][lane];
    #pragma unroll
    for (int k = 0; k < 32; ++k) {
      const float hv = hp[k * 64];
      a0 = fmaf(wh[0][k], hv, a0); a1 = fmaf(wh[1][k], hv, a1);
      a2 = fmaf(wh[2][k], hv, a2); a3 = fmaf(wh[3][k], hv, a3);
    }
    #pragma unroll
    for (int off = 32; off > 0; off >>= 1) {
      a0 += __shfl_down(a0, off, 64);
      a1 += __shfl_down(a1, off, 64);
      a2 += __shfl_down(a2, off, 64);
      a3 += __shfl_down(a3, off, 64);
    }
    if (lane == 0) {
      const float fg = sigmoid_f(a0 + bias[0]);
      const float ig = sigmoid_f(a1 + bias[1]);
      const float gg = tanh_f(a2 + bias[2]);
      const float og = sigmoid_f(a3 + bias[3]);
      creg = fg * creg + ig * gg;
      const float hn = og * tanh_f(creg);
      const unsigned long long pk =
          ((unsigned long long)__float_as_uint(hn) << 32) | (unsigned long long)(unsigned)(t + 1);
      st_agent64(&hbuf[(size_t)((t + 1) & 1) * HID + j], pk);   // publish ASAP
      if (t == T_STEPS - 1) {
        out[(size_t)T_STEPS * NCH + j]       = hn;     // final h
        out[(size_t)T_STEPS * NCH + HID + j] = creg;   // final c
      }
    }

    // ---- logits for step t-1 from already-staged h[t] (rides in wait slack) ----
    if (lcol >= 0 && t > 0) {
      const float* hq = &h_lds[bsel][lane];
      float sacc = 0.0f;
      #pragma unroll
      for (int u = 0; u < 32; ++u) sacc = fmaf(wfc_c[u], hq[u * 64], sacc);
      #pragma unroll
      for (int off = 32; off > 0; off >>= 1) sacc += __shfl_down(sacc, off, 64);
      if (lane == 0) out[(size_t)(t - 1) * NCH + lcol] = sacc + bfc_c;
    }
  }

  // ---- epilogue: stage h[T] (tag T, slot 0) and emit logits for t = T-1 ----
  {
    const unsigned long long* src = hbuf;  // T_STEPS & 1 == 0
    const unsigned ut = (unsigned)T_STEPS;
    unsigned long long v0 = ld_agent64(src + i0), v1 = ld_agent64(src + i1),
                       v2 = ld_agent64(src + i2), v3 = ld_agent64(src + i3);
    while (((unsigned)v0 != ut) | ((unsigned)v1 != ut) |
           ((unsigned)v2 != ut) | ((unsigned)v3 != ut)) {
      if ((unsigned)v0 != ut) v0 = ld_agent64(src + i0);
      if ((unsigned)v1 != ut) v1 = ld_agent64(src + i1);
      if ((unsigned)v2 != ut) v2 = ld_agent64(src + i2);
      if ((unsigned)v3 != ut) v3 = ld_agent64(src + i3);
    }
    h_lds[0][i0] = __uint_as_float((unsigned)(v0 >> 32));
    h_lds[0][i1] = __uint_as_float((unsigned)(v1 >> 32));
    h_lds[0][i2] = __uint_as_float((unsigned)(v2 >> 32));
    h_lds[0][i3] = __uint_as_float((unsigned)(v3 >> 32));
    __syncthreads();
    if (lcol >= 0) {
      const float* hq = &h_lds[0][lane];
      float sacc = 0.0f;
      #pragma unroll
      for (int u = 0; u < 32; ++u) sacc = fmaf(wfc_c[u], hq[u * 64], sacc);
      #pragma unroll
      for (int off = 32; off > 0; off >>= 1) sacc += __shfl_down(sacc, off, 64);
      if (lane == 0) out[(size_t)(T_STEPS - 1) * NCH + lcol] = sacc + bfc_c;
    }
  }
}

extern "C" void kernel_launch(void* const* d_in, const int* in_sizes, int n_in,
                              void* d_out, int out_size, void* d_ws, size_t ws_size,
                              hipStream_t stream) {
  (void)in_sizes; (void)n_in; (void)out_size; (void)ws_size;
  const int* seq     = (const int*)d_in[0];
  const float* emb   = (const float*)d_in[1];
  const float* Wf    = (const float*)d_in[2];
  const float* bfv   = (const float*)d_in[3];
  const float* Wi    = (const float*)d_in[4];
  const float* biv   = (const float*)d_in[5];
  const float* Wg    = (const float*)d_in[6];
  const float* bgv   = (const float*)d_in[7];
  const float* Wo    = (const float*)d_in[8];
  const float* bov   = (const float*)d_in[9];
  const float* Wfc   = (const float*)d_in[10];
  const float* bfc   = (const float*)d_in[11];
  float* out         = (float*)d_out;
  unsigned long long* hbuf = (unsigned long long*)d_ws;   // 2*HID*8 = 32 KB

  hipMemsetAsync(d_ws, 0, 2 * HID * sizeof(unsigned long long), stream);

  void* args[] = {
    (void*)&seq, (void*)&emb,
    (void*)&Wf, (void*)&bfv, (void*)&Wi, (void*)&biv,
    (void*)&Wg, (void*)&bgv, (void*)&Wo, (void*)&bov,
    (void*)&Wfc, (void*)&bfc,
    (void*)&hbuf, (void*)&out
  };
  hipLaunchCooperativeKernel((const void*)lstm_persist, dim3(NBLK), dim3(TPB),
                             args, 0, stream);
}

// Round 3
// 75224.066 us; speedup vs baseline: 1.0755x; 1.0755x over previous
//
#include <hip/hip_runtime.h>
#include <stdint.h>

// CharLSTM persistent-RNN kernel for MI355X. f32 in / f32 out.
// 256 WGs (1/CU) x 512 threads. Wave v of WG w owns neuron j = 8w+v.
// R9:  conflict-free fragment layout; tagged 64-bit h words (f32<<32 | step).
// R10: flag hierarchy: -6.5% only -> congestion theory refuted.
// R11: single-hop tagged polling + x-dot overlapped under h-load flight:
//      neutral -> sync-scheme tweaks exonerated.
// R12: resource round. VGPR_Count=124 < 160 declared weight floats proved the
//      weights were NOT register-resident (default launch_bounds caps at 128
//      VGPR): the hot loop was re-loading spilled weights every step.
//        - __launch_bounds__(TPB, 2): our launch is exactly 1 block/CU =
//          2 waves/SIMD, so allow 256 VGPR/wave -> weights stay in registers.
//        - float4 fragment layout (cols 256k+4l..+3): float4 weight preload,
//          float4 x loads, gate-loop h reads via 8x ds_read_b128 (m134
//          conflict-free pattern) instead of 40x ds_read_b32.
//        - DPP row_shr + readlane reduction: zero DS-pipe shfl ops.

#define T_STEPS 16384
#define HID     2048
#define EMBD    512
#define NCH     128
#define FANIN   (EMBD + HID)
#define NBLK    256
#define TPB     512
#define NEUR_PER_WG 8

static_assert(TPB == EMBD, "index math assumes TPB == EMBD");

__device__ __forceinline__ float sigmoid_f(float x) {
  return 1.0f / (1.0f + __expf(-x));
}
__device__ __forceinline__ float tanh_f(float x) {
  return 1.0f - 2.0f / (__expf(2.0f * x) + 1.0f);
}
__device__ __forceinline__ unsigned long long ld_agent64(const unsigned long long* p) {
  return __hip_atomic_load(p, __ATOMIC_RELAXED, __HIP_MEMORY_SCOPE_AGENT);
}
__device__ __forceinline__ void st_agent64(unsigned long long* p, unsigned long long v) {
  __hip_atomic_store(p, v, __ATOMIC_RELAXED, __HIP_MEMORY_SCOPE_AGENT);
}

// ---- VALU-only wave64 reduction: DPP row_shr tree + readlane of row tails ----
#define DPP_ROW_SHR(n) (0x110 | (n))
__device__ __forceinline__ float row_reduce(float x) {
  x += __int_as_float(__builtin_amdgcn_update_dpp(0, __float_as_int(x), DPP_ROW_SHR(1), 0xF, 0xF, true));
  x += __int_as_float(__builtin_amdgcn_update_dpp(0, __float_as_int(x), DPP_ROW_SHR(2), 0xF, 0xF, true));
  x += __int_as_float(__builtin_amdgcn_update_dpp(0, __float_as_int(x), DPP_ROW_SHR(4), 0xF, 0xF, true));
  x += __int_as_float(__builtin_amdgcn_update_dpp(0, __float_as_int(x), DPP_ROW_SHR(8), 0xF, 0xF, true));
  return x;  // lanes 15/31/47/63 hold their row's sum
}
__device__ __forceinline__ float wave_sum(float x) {
  const int xi = __float_as_int(row_reduce(x));
  return __int_as_float(__builtin_amdgcn_readlane(xi, 15))
       + __int_as_float(__builtin_amdgcn_readlane(xi, 31))
       + __int_as_float(__builtin_amdgcn_readlane(xi, 47))
       + __int_as_float(__builtin_amdgcn_readlane(xi, 63));
}

__global__ __launch_bounds__(TPB, 2) void lstm_persist(
    const int* __restrict__ seq,
    const float* __restrict__ emb,
    const float* __restrict__ Wf, const float* __restrict__ bfv,
    const float* __restrict__ Wi, const float* __restrict__ biv,
    const float* __restrict__ Wg, const float* __restrict__ bgv,
    const float* __restrict__ Wo, const float* __restrict__ bov,
    const float* __restrict__ Wfc, const float* __restrict__ bfc,
    unsigned long long* __restrict__ hbuf,   // [2][HID] tagged h
    float* __restrict__ out)                 // f32: [T][NCH] logits, h[HID], c[HID]
{
  __shared__ __attribute__((aligned(16))) float h_lds[2][HID];

  const int tid  = threadIdx.x;
  const int wv   = tid >> 6;
  const int lane = tid & 63;
  const int j    = blockIdx.x * NEUR_PER_WG + wv;   // neuron this wave owns

  // seq dtype guard (selects int32 on this data; kept for safety)
  int shift = 1;
  for (int k = 0; k < 64; ++k) {
    if (seq[2 * k + 1] != 0) { shift = 0; break; }
  }

  // ---- preload weights, float4 chunks: lane l owns cols {256k+4l..+3} ----
  // (16B/lane coalesced global reads; b128 conflict-free LDS reads in loop)
  const float* Wmat[4] = {Wf, Wi, Wg, Wo};
  const float* bvec[4] = {bfv, biv, bgv, bov};
  float4 wh4[4][8], wx4[4][2];
  float  bias[4];
  #pragma unroll
  for (int g = 0; g < 4; ++g) {
    const float* rp = Wmat[g] + (size_t)j * FANIN;
    const float4* hp4 = reinterpret_cast<const float4*>(rp + EMBD);
    const float4* xp4 = reinterpret_cast<const float4*>(rp);
    #pragma unroll
    for (int k = 0; k < 8; ++k) wh4[g][k] = hp4[k * 64 + lane];
    #pragma unroll
    for (int k = 0; k < 2; ++k) wx4[g][k] = xp4[k * 64 + lane];
    bias[g] = bvec[g][j];
  }

  // ---- logits duty: even WGs' wave 1 each own one output column ----
  int lcol = -1;
  float4 wfc4[8];
  float bfc_c = 0.0f;
  if (((blockIdx.x & 1) == 0) && wv == 1) {
    lcol = blockIdx.x >> 1;                 // 0..127
    const float4* wp4 = reinterpret_cast<const float4*>(Wfc + (size_t)lcol * HID);
    #pragma unroll
    for (int u = 0; u < 8; ++u) wfc4[u] = wp4[u * 64 + lane];
    bfc_c = bfc[lcol];
  }

  float creg = 0.0f;  // cell state (lane 0 only)
  const int i0 = tid, i1 = tid + TPB, i2 = tid + 2 * TPB, i3 = tid + 3 * TPB;

  for (int t = 0; t < T_STEPS; ++t) {
    const int bsel = t & 1;
    const unsigned long long* src = hbuf + (size_t)bsel * HID;
    const unsigned ut = (unsigned)t;

    // ---- issue the 4 tagged h loads first (outstanding during x work) ----
    unsigned long long v0 = ld_agent64(src + i0), v1 = ld_agent64(src + i1),
                       v2 = ld_agent64(src + i2), v3 = ld_agent64(src + i3);

    // ---- x loads (L2-resident emb row, float4 coalesced) ----
    const int s = seq[(size_t)t << shift];
    const float4* xr4 = reinterpret_cast<const float4*>(emb + (size_t)s * EMBD);
    const float4 xv0 = xr4[lane];
    const float4 xv1 = xr4[64 + lane];

    // ---- x-part of the gate dots: independent of h, hides h latency ----
    float a0 = 0.0f, a1 = 0.0f, a2 = 0.0f, a3 = 0.0f;
    #pragma unroll
    for (int g = 0; g < 1; ++g) { }  // (kept trivial; unrolled below)
    {
      #pragma unroll
      for (int k = 0; k < 2; ++k) {
        const float4 xv = (k == 0) ? xv0 : xv1;
        a0 = fmaf(wx4[0][k].x, xv.x, a0); a0 = fmaf(wx4[0][k].y, xv.y, a0);
        a0 = fmaf(wx4[0][k].z, xv.z, a0); a0 = fmaf(wx4[0][k].w, xv.w, a0);
        a1 = fmaf(wx4[1][k].x, xv.x, a1); a1 = fmaf(wx4[1][k].y, xv.y, a1);
        a1 = fmaf(wx4[1][k].z, xv.z, a1); a1 = fmaf(wx4[1][k].w, xv.w, a1);
        a2 = fmaf(wx4[2][k].x, xv.x, a2); a2 = fmaf(wx4[2][k].y, xv.y, a2);
        a2 = fmaf(wx4[2][k].z, xv.z, a2); a2 = fmaf(wx4[2][k].w, xv.w, a2);
        a3 = fmaf(wx4[3][k].x, xv.x, a3); a3 = fmaf(wx4[3][k].y, xv.y, a3);
        a3 = fmaf(wx4[3][k].z, xv.z, a3); a3 = fmaf(wx4[3][k].w, xv.w, a3);
      }
    }

    // ---- single-hop readiness: poll own tagged words, re-issue missing ----
    while (((unsigned)v0 != ut) | ((unsigned)v1 != ut) |
           ((unsigned)v2 != ut) | ((unsigned)v3 != ut)) {
      if ((unsigned)v0 != ut) v0 = ld_agent64(src + i0);
      if ((unsigned)v1 != ut) v1 = ld_agent64(src + i1);
      if ((unsigned)v2 != ut) v2 = ld_agent64(src + i2);
      if ((unsigned)v3 != ut) v3 = ld_agent64(src + i3);
    }
    h_lds[bsel][i0] = __uint_as_float((unsigned)(v0 >> 32));
    h_lds[bsel][i1] = __uint_as_float((unsigned)(v1 >> 32));
    h_lds[bsel][i2] = __uint_as_float((unsigned)(v2 >> 32));
    h_lds[bsel][i3] = __uint_as_float((unsigned)(v3 >> 32));
    __syncthreads();

    // ---- h-part of the gate dots: 8x ds_read_b128, conflict-free ----
    const float4* hp4 = reinterpret_cast<const float4*>(&h_lds[bsel][0]);
    #pragma unroll
    for (int k = 0; k < 8; ++k) {
      const float4 hv = hp4[k * 64 + lane];
      a0 = fmaf(wh4[0][k].x, hv.x, a0); a0 = fmaf(wh4[0][k].y, hv.y, a0);
      a0 = fmaf(wh4[0][k].z, hv.z, a0); a0 = fmaf(wh4[0][k].w, hv.w, a0);
      a1 = fmaf(wh4[1][k].x, hv.x, a1); a1 = fmaf(wh4[1][k].y, hv.y, a1);
      a1 = fmaf(wh4[1][k].z, hv.z, a1); a1 = fmaf(wh4[1][k].w, hv.w, a1);
      a2 = fmaf(wh4[2][k].x, hv.x, a2); a2 = fmaf(wh4[2][k].y, hv.y, a2);
      a2 = fmaf(wh4[2][k].z, hv.z, a2); a2 = fmaf(wh4[2][k].w, hv.w, a2);
      a3 = fmaf(wh4[3][k].x, hv.x, a3); a3 = fmaf(wh4[3][k].y, hv.y, a3);
      a3 = fmaf(wh4[3][k].z, hv.z, a3); a3 = fmaf(wh4[3][k].w, hv.w, a3);
    }

    // ---- VALU-only reduction (no DS-pipe shfl) ----
    const float A0 = wave_sum(a0);
    const float A1 = wave_sum(a1);
    const float A2 = wave_sum(a2);
    const float A3 = wave_sum(a3);

    if (lane == 0) {
      const float fg = sigmoid_f(A0 + bias[0]);
      const float ig = sigmoid_f(A1 + bias[1]);
      const float gg = tanh_f(A2 + bias[2]);
      const float og = sigmoid_f(A3 + bias[3]);
      creg = fg * creg + ig * gg;
      const float hn = og * tanh_f(creg);
      const unsigned long long pk =
          ((unsigned long long)__float_as_uint(hn) << 32) | (unsigned long long)(unsigned)(t + 1);
      st_agent64(&hbuf[(size_t)((t + 1) & 1) * HID + j], pk);   // publish ASAP
      if (t == T_STEPS - 1) {
        out[(size_t)T_STEPS * NCH + j]       = hn;     // final h
        out[(size_t)T_STEPS * NCH + HID + j] = creg;   // final c
      }
    }

    // ---- logits for step t-1 from already-staged h[t] (rides in wait slack) ----
    if (lcol >= 0 && t > 0) {
      const float4* hq4 = reinterpret_cast<const float4*>(&h_lds[bsel][0]);
      float sacc = 0.0f;
      #pragma unroll
      for (int u = 0; u < 8; ++u) {
        const float4 hv = hq4[u * 64 + lane];
        sacc = fmaf(wfc4[u].x, hv.x, sacc); sacc = fmaf(wfc4[u].y, hv.y, sacc);
        sacc = fmaf(wfc4[u].z, hv.z, sacc); sacc = fmaf(wfc4[u].w, hv.w, sacc);
      }
      const float S = wave_sum(sacc);
      if (lane == 0) out[(size_t)(t - 1) * NCH + lcol] = S + bfc_c;
    }
  }

  // ---- epilogue: stage h[T] (tag T, slot 0) and emit logits for t = T-1 ----
  {
    const unsigned long long* src = hbuf;  // T_STEPS & 1 == 0
    const unsigned ut = (unsigned)T_STEPS;
    unsigned long long v0 = ld_agent64(src + i0), v1 = ld_agent64(src + i1),
                       v2 = ld_agent64(src + i2), v3 = ld_agent64(src + i3);
    while (((unsigned)v0 != ut) | ((unsigned)v1 != ut) |
           ((unsigned)v2 != ut) | ((unsigned)v3 != ut)) {
      if ((unsigned)v0 != ut) v0 = ld_agent64(src + i0);
      if ((unsigned)v1 != ut) v1 = ld_agent64(src + i1);
      if ((unsigned)v2 != ut) v2 = ld_agent64(src + i2);
      if ((unsigned)v3 != ut) v3 = ld_agent64(src + i3);
    }
    h_lds[0][i0] = __uint_as_float((unsigned)(v0 >> 32));
    h_lds[0][i1] = __uint_as_float((unsigned)(v1 >> 32));
    h_lds[0][i2] = __uint_as_float((unsigned)(v2 >> 32));
    h_lds[0][i3] = __uint_as_float((unsigned)(v3 >> 32));
    __syncthreads();
    if (lcol >= 0) {
      const float4* hq4 = reinterpret_cast<const float4*>(&h_lds[0][0]);
      float sacc = 0.0f;
      #pragma unroll
      for (int u = 0; u < 8; ++u) {
        const float4 hv = hq4[u * 64 + lane];
        sacc = fmaf(wfc4[u].x, hv.x, sacc); sacc = fmaf(wfc4[u].y, hv.y, sacc);
        sacc = fmaf(wfc4[u].z, hv.z, sacc); sacc = fmaf(wfc4[u].w, hv.w, sacc);
      }
      const float S = wave_sum(sacc);
      if (lane == 0) out[(size_t)(T_STEPS - 1) * NCH + lcol] = S + bfc_c;
    }
  }
}

extern "C" void kernel_launch(void* const* d_in, const int* in_sizes, int n_in,
                              void* d_out, int out_size, void* d_ws, size_t ws_size,
                              hipStream_t stream) {
  (void)in_sizes; (void)n_in; (void)out_size; (void)ws_size;
  const int* seq     = (const int*)d_in[0];
  const float* emb   = (const float*)d_in[1];
  const float* Wf    = (const float*)d_in[2];
  const float* bfv   = (const float*)d_in[3];
  const float* Wi    = (const float*)d_in[4];
  const float* biv   = (const float*)d_in[5];
  const float* Wg    = (const float*)d_in[6];
  const float* bgv   = (const float*)d_in[7];
  const float* Wo    = (const float*)d_in[8];
  const float* bov   = (const float*)d_in[9];
  const float* Wfc   = (const float*)d_in[10];
  const float* bfc   = (const float*)d_in[11];
  float* out         = (float*)d_out;
  unsigned long long* hbuf = (unsigned long long*)d_ws;   // 2*HID*8 = 32 KB

  hipMemsetAsync(d_ws, 0, 2 * HID * sizeof(unsigned long long), stream);

  void* args[] = {
    (void*)&seq, (void*)&emb,
    (void*)&Wf, (void*)&bfv, (void*)&Wi, (void*)&biv,
    (void*)&Wg, (void*)&bgv, (void*)&Wo, (void*)&bov,
    (void*)&Wfc, (void*)&bfc,
    (void*)&hbuf, (void*)&out
  };
  hipLaunchCooperativeKernel((const void*)lstm_persist, dim3(NBLK), dim3(TPB),
                             args, 0, stream);
}

// Round 4
// 43261.832 us; speedup vs baseline: 1.8701x; 1.7388x over previous
//
#include <hip/hip_runtime.h>
#include <stdint.h>

// CharLSTM persistent-RNN kernel for MI355X. f32 in / f32 out.
// 256 WGs (1/CU) x 512 threads. Wave v of WG w owns neuron j = 8w+v.
// R9:  conflict-free fragment layout; tagged 64-bit h words (f32<<32 | step).
// R10: flag hierarchy: -6.5% -> naive congestion theory refuted (but it
//      concentrated polls on 4 lines -- per-line queueing got worse).
// R11: single-hop polling + x-dot overlap: neutral -> sync hops exonerated.
// R12: float4 fragments, ds_read_b128, DPP reduce, launch_bounds(,2):
//      -3%; VGPR stayed 124 -> spill is L1-served, secondary.
//      Dispatches now rock-stable 73.4 ms; VALUBusy 24% => ~45 poll
//      rounds/step => consumers spin the whole step.
// R13: per-LINE service contention attack (the surviving theory: 256 WGs
//      polling each 64B hbuf line queue ahead of the one store that would
//      satisfy them):
//        - s_sleep(2) backoff in all retry loops: ~5-10x fewer requests
//          per line per step, costs <=128 cyc detection latency.
//        - coalesced publish: WG's 8 neuron results collected in LDS, then
//          wave 0 lanes 0-7 issue ONE global_store_dwordx2 covering the
//          WG's full 64B line (replaces 8 scattered stores from 8 waves =
//          8 serialized partial-line merges at the coherence point).

#define T_STEPS 16384
#define HID     2048
#define EMBD    512
#define NCH     128
#define FANIN   (EMBD + HID)
#define NBLK    256
#define TPB     512
#define NEUR_PER_WG 8

static_assert(TPB == EMBD, "index math assumes TPB == EMBD");

__device__ __forceinline__ float sigmoid_f(float x) {
  return 1.0f / (1.0f + __expf(-x));
}
__device__ __forceinline__ float tanh_f(float x) {
  return 1.0f - 2.0f / (__expf(2.0f * x) + 1.0f);
}
__device__ __forceinline__ unsigned long long ld_agent64(const unsigned long long* p) {
  return __hip_atomic_load(p, __ATOMIC_RELAXED, __HIP_MEMORY_SCOPE_AGENT);
}
__device__ __forceinline__ void st_agent64(unsigned long long* p, unsigned long long v) {
  __hip_atomic_store(p, v, __ATOMIC_RELAXED, __HIP_MEMORY_SCOPE_AGENT);
}

// ---- VALU-only wave64 reduction: DPP row_shr tree + readlane of row tails ----
#define DPP_ROW_SHR(n) (0x110 | (n))
__device__ __forceinline__ float row_reduce(float x) {
  x += __int_as_float(__builtin_amdgcn_update_dpp(0, __float_as_int(x), DPP_ROW_SHR(1), 0xF, 0xF, true));
  x += __int_as_float(__builtin_amdgcn_update_dpp(0, __float_as_int(x), DPP_ROW_SHR(2), 0xF, 0xF, true));
  x += __int_as_float(__builtin_amdgcn_update_dpp(0, __float_as_int(x), DPP_ROW_SHR(4), 0xF, 0xF, true));
  x += __int_as_float(__builtin_amdgcn_update_dpp(0, __float_as_int(x), DPP_ROW_SHR(8), 0xF, 0xF, true));
  return x;  // lanes 15/31/47/63 hold their row's sum
}
__device__ __forceinline__ float wave_sum(float x) {
  const int xi = __float_as_int(row_reduce(x));
  return __int_as_float(__builtin_amdgcn_readlane(xi, 15))
       + __int_as_float(__builtin_amdgcn_readlane(xi, 31))
       + __int_as_float(__builtin_amdgcn_readlane(xi, 47))
       + __int_as_float(__builtin_amdgcn_readlane(xi, 63));
}

__global__ __launch_bounds__(TPB, 2) void lstm_persist(
    const int* __restrict__ seq,
    const float* __restrict__ emb,
    const float* __restrict__ Wf, const float* __restrict__ bfv,
    const float* __restrict__ Wi, const float* __restrict__ biv,
    const float* __restrict__ Wg, const float* __restrict__ bgv,
    const float* __restrict__ Wo, const float* __restrict__ bov,
    const float* __restrict__ Wfc, const float* __restrict__ bfc,
    unsigned long long* __restrict__ hbuf,   // [2][HID] tagged h
    float* __restrict__ out)                 // f32: [T][NCH] logits, h[HID], c[HID]
{
  __shared__ __attribute__((aligned(16))) float h_lds[2][HID];
  __shared__ float hout[NEUR_PER_WG];   // per-step collected neuron outputs

  const int tid  = threadIdx.x;
  const int wv   = tid >> 6;
  const int lane = tid & 63;
  const int j    = blockIdx.x * NEUR_PER_WG + wv;   // neuron this wave owns

  // seq dtype guard (selects int32 on this data; kept for safety)
  int shift = 1;
  for (int k = 0; k < 64; ++k) {
    if (seq[2 * k + 1] != 0) { shift = 0; break; }
  }

  // ---- preload weights, float4 chunks: lane l owns cols {256k+4l..+3} ----
  const float* Wmat[4] = {Wf, Wi, Wg, Wo};
  const float* bvec[4] = {bfv, biv, bgv, bov};
  float4 wh4[4][8], wx4[4][2];
  float  bias[4];
  #pragma unroll
  for (int g = 0; g < 4; ++g) {
    const float* rp = Wmat[g] + (size_t)j * FANIN;
    const float4* hp4 = reinterpret_cast<const float4*>(rp + EMBD);
    const float4* xp4 = reinterpret_cast<const float4*>(rp);
    #pragma unroll
    for (int k = 0; k < 8; ++k) wh4[g][k] = hp4[k * 64 + lane];
    #pragma unroll
    for (int k = 0; k < 2; ++k) wx4[g][k] = xp4[k * 64 + lane];
    bias[g] = bvec[g][j];
  }

  // ---- logits duty: even WGs' wave 1 each own one output column ----
  int lcol = -1;
  float4 wfc4[8];
  float bfc_c = 0.0f;
  if (((blockIdx.x & 1) == 0) && wv == 1) {
    lcol = blockIdx.x >> 1;                 // 0..127
    const float4* wp4 = reinterpret_cast<const float4*>(Wfc + (size_t)lcol * HID);
    #pragma unroll
    for (int u = 0; u < 8; ++u) wfc4[u] = wp4[u * 64 + lane];
    bfc_c = bfc[lcol];
  }

  float creg = 0.0f;  // cell state (lane 0 only)
  const int i0 = tid, i1 = tid + TPB, i2 = tid + 2 * TPB, i3 = tid + 3 * TPB;

  for (int t = 0; t < T_STEPS; ++t) {
    const int bsel = t & 1;
    const unsigned long long* src = hbuf + (size_t)bsel * HID;
    const unsigned ut = (unsigned)t;

    // ---- issue the 4 tagged h loads first (outstanding during x work) ----
    unsigned long long v0 = ld_agent64(src + i0), v1 = ld_agent64(src + i1),
                       v2 = ld_agent64(src + i2), v3 = ld_agent64(src + i3);

    // ---- x loads (L2-resident emb row, float4 coalesced) ----
    const int s = seq[(size_t)t << shift];
    const float4* xr4 = reinterpret_cast<const float4*>(emb + (size_t)s * EMBD);
    const float4 xv0 = xr4[lane];
    const float4 xv1 = xr4[64 + lane];

    // ---- x-part of the gate dots: independent of h, hides h latency ----
    float a0 = 0.0f, a1 = 0.0f, a2 = 0.0f, a3 = 0.0f;
    #pragma unroll
    for (int k = 0; k < 2; ++k) {
      const float4 xv = (k == 0) ? xv0 : xv1;
      a0 = fmaf(wx4[0][k].x, xv.x, a0); a0 = fmaf(wx4[0][k].y, xv.y, a0);
      a0 = fmaf(wx4[0][k].z, xv.z, a0); a0 = fmaf(wx4[0][k].w, xv.w, a0);
      a1 = fmaf(wx4[1][k].x, xv.x, a1); a1 = fmaf(wx4[1][k].y, xv.y, a1);
      a1 = fmaf(wx4[1][k].z, xv.z, a1); a1 = fmaf(wx4[1][k].w, xv.w, a1);
      a2 = fmaf(wx4[2][k].x, xv.x, a2); a2 = fmaf(wx4[2][k].y, xv.y, a2);
      a2 = fmaf(wx4[2][k].z, xv.z, a2); a2 = fmaf(wx4[2][k].w, xv.w, a2);
      a3 = fmaf(wx4[3][k].x, xv.x, a3); a3 = fmaf(wx4[3][k].y, xv.y, a3);
      a3 = fmaf(wx4[3][k].z, xv.z, a3); a3 = fmaf(wx4[3][k].w, xv.w, a3);
    }

    // ---- single-hop readiness with s_sleep backoff ----
    while (((unsigned)v0 != ut) | ((unsigned)v1 != ut) |
           ((unsigned)v2 != ut) | ((unsigned)v3 != ut)) {
      __builtin_amdgcn_s_sleep(2);   // ~128 cyc: cut per-line request storm
      if ((unsigned)v0 != ut) v0 = ld_agent64(src + i0);
      if ((unsigned)v1 != ut) v1 = ld_agent64(src + i1);
      if ((unsigned)v2 != ut) v2 = ld_agent64(src + i2);
      if ((unsigned)v3 != ut) v3 = ld_agent64(src + i3);
    }
    h_lds[bsel][i0] = __uint_as_float((unsigned)(v0 >> 32));
    h_lds[bsel][i1] = __uint_as_float((unsigned)(v1 >> 32));
    h_lds[bsel][i2] = __uint_as_float((unsigned)(v2 >> 32));
    h_lds[bsel][i3] = __uint_as_float((unsigned)(v3 >> 32));
    __syncthreads();

    // ---- h-part of the gate dots: 8x ds_read_b128, conflict-free ----
    const float4* hp4 = reinterpret_cast<const float4*>(&h_lds[bsel][0]);
    #pragma unroll
    for (int k = 0; k < 8; ++k) {
      const float4 hv = hp4[k * 64 + lane];
      a0 = fmaf(wh4[0][k].x, hv.x, a0); a0 = fmaf(wh4[0][k].y, hv.y, a0);
      a0 = fmaf(wh4[0][k].z, hv.z, a0); a0 = fmaf(wh4[0][k].w, hv.w, a0);
      a1 = fmaf(wh4[1][k].x, hv.x, a1); a1 = fmaf(wh4[1][k].y, hv.y, a1);
      a1 = fmaf(wh4[1][k].z, hv.z, a1); a1 = fmaf(wh4[1][k].w, hv.w, a1);
      a2 = fmaf(wh4[2][k].x, hv.x, a2); a2 = fmaf(wh4[2][k].y, hv.y, a2);
      a2 = fmaf(wh4[2][k].z, hv.z, a2); a2 = fmaf(wh4[2][k].w, hv.w, a2);
      a3 = fmaf(wh4[3][k].x, hv.x, a3); a3 = fmaf(wh4[3][k].y, hv.y, a3);
      a3 = fmaf(wh4[3][k].z, hv.z, a3); a3 = fmaf(wh4[3][k].w, hv.w, a3);
    }

    // ---- VALU-only reduction (no DS-pipe shfl) ----
    const float A0 = wave_sum(a0);
    const float A1 = wave_sum(a1);
    const float A2 = wave_sum(a2);
    const float A3 = wave_sum(a3);

    if (lane == 0) {
      const float fg = sigmoid_f(A0 + bias[0]);
      const float ig = sigmoid_f(A1 + bias[1]);
      const float gg = tanh_f(A2 + bias[2]);
      const float og = sigmoid_f(A3 + bias[3]);
      creg = fg * creg + ig * gg;
      const float hn = og * tanh_f(creg);
      hout[wv] = hn;                          // collect for coalesced publish
      if (t == T_STEPS - 1) {
        out[(size_t)T_STEPS * NCH + j]       = hn;     // final h
        out[(size_t)T_STEPS * NCH + HID + j] = creg;   // final c
      }
    }
    __syncthreads();   // hout[] complete

    // ---- coalesced publish: ONE 64B line store by wave 0 lanes 0..7 ----
    if (wv == 0 && lane < NEUR_PER_WG) {
      const unsigned long long pk =
          ((unsigned long long)__float_as_uint(hout[lane]) << 32) |
          (unsigned long long)(unsigned)(t + 1);
      st_agent64(&hbuf[(size_t)((t + 1) & 1) * HID +
                       (size_t)blockIdx.x * NEUR_PER_WG + lane], pk);
    }

    // ---- logits for step t-1 from already-staged h[t] (rides in wait slack) ----
    if (lcol >= 0 && t > 0) {
      const float4* hq4 = reinterpret_cast<const float4*>(&h_lds[bsel][0]);
      float sacc = 0.0f;
      #pragma unroll
      for (int u = 0; u < 8; ++u) {
        const float4 hv = hq4[u * 64 + lane];
        sacc = fmaf(wfc4[u].x, hv.x, sacc); sacc = fmaf(wfc4[u].y, hv.y, sacc);
        sacc = fmaf(wfc4[u].z, hv.z, sacc); sacc = fmaf(wfc4[u].w, hv.w, sacc);
      }
      const float S = wave_sum(sacc);
      if (lane == 0) out[(size_t)(t - 1) * NCH + lcol] = S + bfc_c;
    }
  }

  // ---- epilogue: stage h[T] (tag T, slot 0) and emit logits for t = T-1 ----
  {
    const unsigned long long* src = hbuf;  // T_STEPS & 1 == 0
    const unsigned ut = (unsigned)T_STEPS;
    unsigned long long v0 = ld_agent64(src + i0), v1 = ld_agent64(src + i1),
                       v2 = ld_agent64(src + i2), v3 = ld_agent64(src + i3);
    while (((unsigned)v0 != ut) | ((unsigned)v1 != ut) |
           ((unsigned)v2 != ut) | ((unsigned)v3 != ut)) {
      __builtin_amdgcn_s_sleep(2);
      if ((unsigned)v0 != ut) v0 = ld_agent64(src + i0);
      if ((unsigned)v1 != ut) v1 = ld_agent64(src + i1);
      if ((unsigned)v2 != ut) v2 = ld_agent64(src + i2);
      if ((unsigned)v3 != ut) v3 = ld_agent64(src + i3);
    }
    h_lds[0][i0] = __uint_as_float((unsigned)(v0 >> 32));
    h_lds[0][i1] = __uint_as_float((unsigned)(v1 >> 32));
    h_lds[0][i2] = __uint_as_float((unsigned)(v2 >> 32));
    h_lds[0][i3] = __uint_as_float((unsigned)(v3 >> 32));
    __syncthreads();
    if (lcol >= 0) {
      const float4* hq4 = reinterpret_cast<const float4*>(&h_lds[0][0]);
      float sacc = 0.0f;
      #pragma unroll
      for (int u = 0; u < 8; ++u) {
        const float4 hv = hq4[u * 64 + lane];
        sacc = fmaf(wfc4[u].x, hv.x, sacc); sacc = fmaf(wfc4[u].y, hv.y, sacc);
        sacc = fmaf(wfc4[u].z, hv.z, sacc); sacc = fmaf(wfc4[u].w, hv.w, sacc);
      }
      const float S = wave_sum(sacc);
      if (lane == 0) out[(size_t)(T_STEPS - 1) * NCH + lcol] = S + bfc_c;
    }
  }
}

extern "C" void kernel_launch(void* const* d_in, const int* in_sizes, int n_in,
                              void* d_out, int out_size, void* d_ws, size_t ws_size,
                              hipStream_t stream) {
  (void)in_sizes; (void)n_in; (void)out_size; (void)ws_size;
  const int* seq     = (const int*)d_in[0];
  const float* emb   = (const float*)d_in[1];
  const float* Wf    = (const float*)d_in[2];
  const float* bfv   = (const float*)d_in[3];
  const float* Wi    = (const float*)d_in[4];
  const float* biv   = (const float*)d_in[5];
  const float* Wg    = (const float*)d_in[6];
  const float* bgv   = (const float*)d_in[7];
  const float* Wo    = (const float*)d_in[8];
  const float* bov   = (const float*)d_in[9];
  const float* Wfc   = (const float*)d_in[10];
  const float* bfc   = (const float*)d_in[11];
  float* out         = (float*)d_out;
  unsigned long long* hbuf = (unsigned long long*)d_ws;   // 2*HID*8 = 32 KB

  hipMemsetAsync(d_ws, 0, 2 * HID * sizeof(unsigned long long), stream);

  void* args[] = {
    (void*)&seq, (void*)&emb,
    (void*)&Wf, (void*)&bfv, (void*)&Wi, (void*)&biv,
    (void*)&Wg, (void*)&bgv, (void*)&Wo, (void*)&bov,
    (void*)&Wfc, (void*)&bfc,
    (void*)&hbuf, (void*)&out
  };
  hipLaunchCooperativeKernel((const void*)lstm_persist, dim3(NBLK), dim3(TPB),
                             args, 0, stream);
}